// Round 1
// baseline (354.086 us; speedup 1.0000x reference)
//
#include <hip/hip_runtime.h>
#include <hip/hip_bf16.h>

typedef __bf16 bf16x8 __attribute__((ext_vector_type(8)));
typedef unsigned short u16x8 __attribute__((ext_vector_type(8)));
typedef float f32x4 __attribute__((ext_vector_type(4)));

__device__ __forceinline__ unsigned short f2bf(float f) {
    unsigned u = __builtin_bit_cast(unsigned, f);
    u += 0x7FFFu + ((u >> 16) & 1u);            // RNE
    return (unsigned short)(u >> 16);
}
__device__ __forceinline__ float bf2f(unsigned short h) {
    unsigned u = ((unsigned)h) << 16;
    return __builtin_bit_cast(float, u);
}

// ---------------------------------------------------------------------------
// Pre-kernel: w2 (128,3,256) fp32 -> w2t[i][kappa] bf16, kappa = k*128 + j2
// (tap-major K so every 32-wide MFMA k-step lies within a single tap)
// ---------------------------------------------------------------------------
__global__ void prep_w2(const float* __restrict__ w2, unsigned short* __restrict__ w2t) {
    int idx = blockIdx.x * 256 + threadIdx.x;   // over input layout, coalesced reads
    if (idx < 128 * 3 * 256) {
        int i  = idx % 256;
        int jk = idx / 256;                     // j2*3 + k
        int j2 = jk / 3, k = jk % 3;
        w2t[i * 384 + k * 128 + j2] = f2bf(w2[idx]);
    }
}

// ---------------------------------------------------------------------------
// Main fused kernel: one block per m.
//   stage x4[m] -> LDS (transposed, bf16)  ->  MFMA GEMM (196x256, K=384)
//   -> per-wave LDS C-buffer -> fused roll/w1 epilogue -> coalesced stores
// ---------------------------------------------------------------------------
__global__ __launch_bounds__(256, 2) void fused_conv_outer(
    const float* __restrict__ x, const float* __restrict__ w1,
    const unsigned short* __restrict__ w2t, float* __restrict__ out)
{
    // x_lds[row = l*14+h][j2], row stride 136 bf16 = 272 B (16B-aligned, 68 words == 4 mod 32)
    __shared__ alignas(16) unsigned short xlds[196 * 136];          // 53,312 B
    // per-wave C buffer: cb[wave][c16][r], r-stride 210 (105 words, odd -> conflict-free writes)
    __shared__ alignas(16) unsigned short cb[4 * 16 * 210];         // 26,880 B

    const int m    = blockIdx.x;
    const int tid  = threadIdx.x;
    const int wave = tid >> 6;
    const int lane = tid & 63;
    const int c16  = lane & 15;      // MFMA "own-dim" index (A-row / B-col / C-col)
    const int kgrp = lane >> 4;      // 0..3: k-subgroup (A/B), row-subgroup (C/D)

    // ---------------- stage x4[m] -> xlds (bf16, transposed) ----------------
    {
        const float* xm = x + (size_t)m * 25088;       // x4[m][j2][l][h], j2 stride 196
        const int j2a = 2 * lane;                      // each lane owns 2 consecutive j2
        const int rbase = wave * 48;
        const int rend  = (wave == 3) ? 52 : 48;       // wave3 takes rows 144..195
        for (int rr = 0; rr < rend; rr += 4) {
            const float4 v0 = *(const float4*)(xm + (size_t)j2a * 196 + rbase + rr);
            const float4 v1 = *(const float4*)(xm + (size_t)(j2a + 1) * 196 + rbase + rr);
            const float a0[4] = {v0.x, v0.y, v0.z, v0.w};
            const float a1[4] = {v1.x, v1.y, v1.z, v1.w};
#pragma unroll
            for (int i2 = 0; i2 < 4; ++i2) {
                unsigned pk = (unsigned)f2bf(a0[i2]) | ((unsigned)f2bf(a1[i2]) << 16);
                *(unsigned*)&xlds[(rbase + rr + i2) * 136 + j2a] = pk;   // bank = lane%32: free
            }
        }
    }
    __syncthreads();

    unsigned short* cbw = &cb[wave * (16 * 210)];

#pragma unroll 1
    for (int nt = 0; nt < 4; ++nt) {
        const int ntile = wave * 4 + nt;
        const int col   = ntile * 16 + c16;

        // ---- B fragments for this 16-col tile, all 12 k-steps (L1/L2-hit) ----
        bf16x8 Bf[12];
        {
            const unsigned short* bp = w2t + (size_t)col * 384 + kgrp * 8;
#pragma unroll
            for (int k = 0; k < 12; ++k)
                Bf[k] = __builtin_bit_cast(bf16x8, *(const u16x8*)(bp + k * 32));
        }

#pragma unroll 1
        for (int mt = 0; mt < 13; ++mt) {
            const int r0 = mt * 16 + c16;              // GEMM row this lane feeds as A
            const int rc = (r0 < 196) ? r0 : 195;      // clamp pad rows (results discarded)
            const int nn = rc % 14;                    // spatial n of this row

            bf16x8 Af[12];
#pragma unroll
            for (int k = 0; k < 12; ++k) {
                const int tap = k >> 2;                // kappa/128
                const int h   = nn + tap - 1;          // window position
                if ((unsigned)h < 14u) {
                    // row l*14+h = rc + tap - 1 ; 8 consecutive j2 -> one ds_read_b128
                    Af[k] = __builtin_bit_cast(bf16x8,
                        *(const u16x8*)&xlds[(rc + tap - 1) * 136 + (k & 3) * 32 + kgrp * 8]);
                } else {
                    Af[k] = __builtin_bit_cast(bf16x8, (u16x8)(unsigned short)0);
                }
            }

            f32x4 acc = {0.f, 0.f, 0.f, 0.f};
#pragma unroll
            for (int k = 0; k < 12; ++k)
                acc = __builtin_amdgcn_mfma_f32_16x16x32_bf16(Af[k], Bf[k], acc, 0, 0, 0);

            // C/D layout: col = lane&15, row = kgrp*4 + reg  -> pack rows pairwise as bf16
            const int rr0 = mt * 16 + kgrp * 4;
            if (rr0 < 196) {
                unsigned pk0 = (unsigned)f2bf(acc[0]) | ((unsigned)f2bf(acc[1]) << 16);
                unsigned pk1 = (unsigned)f2bf(acc[2]) | ((unsigned)f2bf(acc[3]) << 16);
                *(unsigned*)&cbw[c16 * 210 + rr0]     = pk0;
                *(unsigned*)&cbw[c16 * 210 + rr0 + 2] = pk1;
            }
        }

        // ---------------- fused epilogue for these 16 output channels ----------------
        // out[m,i,cdx,n] = w1[i,0]*t4[(cdx+13)%14, n, i] + w1[i,1]*t4[(cdx+12)%14, n, i]
        int r1a[4], r2a[4], ea[4]; bool oka[4];
#pragma unroll
        for (int it = 0; it < 4; ++it) {
            int e = it * 64 + lane;
            oka[it] = (e < 196);
            int ec  = oka[it] ? e : 195;
            int cdx = ec / 14;
            int nn2 = ec - cdx * 14;
            r1a[it] = ((cdx + 13) % 14) * 14 + nn2;
            r2a[it] = ((cdx + 12) % 14) * 14 + nn2;
            ea[it]  = e;
        }
        float* outb = out + (size_t)m * 50176 + (size_t)ntile * 16 * 196;
#pragma unroll
        for (int c = 0; c < 16; ++c) {
            const float2 wv = *(const float2*)(w1 + (ntile * 16 + c) * 2);  // uniform -> s_load
            const unsigned short* cr = cbw + c * 210;
            float* op = outb + c * 196;
#pragma unroll
            for (int it = 0; it < 4; ++it) {
                if (oka[it]) {
                    float v = wv.x * bf2f(cr[r1a[it]]) + wv.y * bf2f(cr[r2a[it]]);
                    op[ea[it]] = v;                       // coalesced dword stores
                }
            }
        }
    }
}

extern "C" void kernel_launch(void* const* d_in, const int* in_sizes, int n_in,
                              void* d_out, int out_size, void* d_ws, size_t ws_size,
                              hipStream_t stream) {
    const float* x  = (const float*)d_in[0];   // (1024,1792,14) fp32
    const float* w1 = (const float*)d_in[1];   // (256,2) fp32
    const float* w2 = (const float*)d_in[2];   // (128,3,256) fp32
    float* out = (float*)d_out;                // (1024,256,14,14) fp32
    unsigned short* w2t = (unsigned short*)d_ws;  // 256*384 bf16 = 196,608 B

    prep_w2<<<384, 256, 0, stream>>>(w2, w2t);
    fused_conv_outer<<<1024, 256, 0, stream>>>(x, w1, w2t, out);
}